// Round 9
// baseline (272.946 us; speedup 1.0000x reference)
//
#include <hip/hip_runtime.h>
#include <math.h>

#define NPIX 16384      // H*W
#define CCH  512        // channels
#define MS   262144     // 512*512

typedef unsigned short u16;
typedef unsigned int u32;
typedef __attribute__((ext_vector_type(8))) short bf16x8;   // 8 bf16 = 4 VGPR
typedef __attribute__((ext_vector_type(4))) float f32x4;

__device__ __forceinline__ u16 f2bf(float f) {
  u32 u = __builtin_bit_cast(u32, f);
  u += 0x7fffu + ((u >> 16) & 1u);    // round-to-nearest-even
  return (u16)(u >> 16);
}
__device__ __forceinline__ float b2f(u16 h) {
  u32 u = ((u32)h) << 16;
  return __builtin_bit_cast(float, u);
}

typedef const __attribute__((address_space(1))) u32* gp_t;
typedef __attribute__((address_space(3))) u32* lp_t;
__device__ __forceinline__ void gl_lds16(const void* g, void* l) {
  __builtin_amdgcn_global_load_lds((gp_t)g, (lp_t)l, 16, 0, 0);
}

// ---- Kt=128 staged tile, XOR chunk swizzle (LDS row = 128 bf16 = 16x16B chunks)
__device__ __forceinline__ void stage4(const u16* tile, size_t stride, int rl,
                                       int k0, u16* lds, int lane) {
  int lr = lane >> 4;                               // 4 rows per instruction
  int cg2 = (lane & 15) ^ ((rl + lr) & 15);         // swizzled global chunk
  gl_lds16(tile + (size_t)(rl + lr) * stride + k0 + cg2 * 8,
           lds + (size_t)rl * 128);
}
__device__ __forceinline__ bf16x8 fragld(const u16* lds, int row, int cl) {
  return *(const bf16x8*)&lds[(size_t)row * 128 + (size_t)((cl ^ (row & 15)) << 3)];
}

// ---- Kt=64 variants (LDS row = 64 bf16 = 8x16B chunks); 8 rows per gl_lds16
__device__ __forceinline__ void stage8_64(const u16* tile, size_t stride, int rl,
                                          int k0, u16* lds, int lane) {
  int lr = lane >> 3;                               // 8 rows per instruction
  int cg2 = (lane & 7) ^ ((rl + lr) & 7);           // swizzled global chunk
  gl_lds16(tile + (size_t)(rl + lr) * stride + k0 + cg2 * 8,
           lds + (size_t)rl * 64);
}
__device__ __forceinline__ bf16x8 fragld64(const u16* lds, int row, int cl) {
  return *(const bf16x8*)&lds[(size_t)row * 64 + (size_t)((cl ^ (row & 7)) << 3)];
}

// ---- Kt=32 variants (LDS row = 32 bf16 = 4x16B chunks); 16 rows per gl_lds16
__device__ __forceinline__ void stage16_32(const u16* tile, size_t stride, int rl,
                                           int k0, u16* lds, int lane) {
  int lr = lane >> 2;                               // 16 rows per instruction
  int cg2 = (lane & 3) ^ ((rl + lr) & 3);           // swizzled global chunk
  gl_lds16(tile + (size_t)(rl + lr) * stride + k0 + cg2 * 8,
           lds + (size_t)rl * 32);
}
__device__ __forceinline__ bf16x8 fragld32(const u16* lds, int row, int cl) {
  return *(const bf16x8*)&lds[(size_t)row * 32 + (size_t)((cl ^ (row & 3)) << 3)];
}

// ================= prep: one pass over X -> bucketed colsum partials,
// fct (bf16 [c][n]), fcb (bf16 [n][c]).
__global__ __launch_bounds__(256) void prep_k(const float* __restrict__ Xc,
                                              const float* __restrict__ Xs,
                                              float* __restrict__ s16,
                                              u16* __restrict__ fct,
                                              u16* __restrict__ fcb) {
  int b = blockIdx.z;
  const float* X = b ? Xs : Xc;
  u16* outT = fct + (size_t)b * ((size_t)CCH * NPIX);
  __shared__ float T[64][65];
  __shared__ float red2[64][4];
  int n0 = blockIdx.x * 64, c0 = blockIdx.y * 64;
  int t = threadIdx.x;
  int cr = t & 15, nr = t >> 4;
  #pragma unroll
  for (int rr = 0; rr < 4; ++rr) {
    int n = nr + rr * 16;
    float4 v = *(const float4*)&X[(size_t)(n0 + n) * CCH + c0 + cr * 4];
    T[n][cr * 4 + 0] = v.x;
    T[n][cr * 4 + 1] = v.y;
    T[n][cr * 4 + 2] = v.z;
    T[n][cr * 4 + 3] = v.w;
    if (b == 0) {
      ushort4 q;
      q.x = f2bf(v.x); q.y = f2bf(v.y); q.z = f2bf(v.z); q.w = f2bf(v.w);
      *(ushort4*)&fcb[(size_t)(n0 + n) * CCH + c0 + cr * 4] = q;
    }
  }
  __syncthreads();
  int cl = t >> 2, np = (t & 3) * 16;
  size_t obase = (size_t)(c0 + cl) * NPIX + n0 + np;
  float s = 0.f;
  u16 ov[16];
  #pragma unroll
  for (int i = 0; i < 16; i += 4) {
    float v0 = T[np + i + 0][cl], v1 = T[np + i + 1][cl];
    float v2 = T[np + i + 2][cl], v3 = T[np + i + 3][cl];
    s += v0 + v1 + v2 + v3;
    ov[i + 0] = f2bf(v0); ov[i + 1] = f2bf(v1);
    ov[i + 2] = f2bf(v2); ov[i + 3] = f2bf(v3);
  }
  *(bf16x8*)&outT[obase + 0] = *(bf16x8*)&ov[0];   // 16B stores
  *(bf16x8*)&outT[obase + 8] = *(bf16x8*)&ov[8];
  red2[cl][t & 3] = s;
  __syncthreads();
  if (t < 64) {
    float cs = red2[t][0] + red2[t][1] + red2[t][2] + red2[t][3];
    atomicAdd(&s16[(blockIdx.x & 15) * 1024 + b * CCH + c0 + t], cs);
  }
}

// ================= Gram partials: 64x128 tiles, Kt=32, 24 KB LDS.
// Grid: 16 kc x (8 rp x 4 cp) x 2 b = 1024 blocks = 4/CU co-resident.
// K=1024 per block in ascending 32-chunks -> per-element MFMA order identical
// to the old 128x128/Kt=64 version -> bit-identical partial sums.
__global__ __launch_bounds__(256, 4) void gram_part(const u16* __restrict__ fct,
                                                    float* __restrict__ Gp,
                                                    const float* __restrict__ s16,
                                                    float* __restrict__ sums) {
  int kc = blockIdx.x;               // 0..15, K chunk of 1024
  int rp = blockIdx.y >> 2;          // 0..7, 64-row panel of G
  int cp = blockIdx.y & 3;           // 0..3, 128-col panel of G
  int b = blockIdx.z;
  int tid = threadIdx.x;
  if (kc == 0 && blockIdx.y == 0) {
    // fold: sums[b][c] = sum over 16 buckets (L2-hot from prep)
    #pragma unroll
    for (int c = tid; c < CCH; c += 256) {
      float s = 0.f;
      #pragma unroll
      for (int k = 0; k < 16; ++k) s += s16[k * 1024 + b * CCH + c];
      sums[b * CCH + c] = s;
    }
  }
  const u16* Xb = fct + (size_t)b * ((size_t)CCH * NPIX);
  __shared__ u16 As[2][64 * 32];     // 2 x 4 KB
  __shared__ u16 Bs[2][128 * 32];    // 2 x 8 KB   (total 24 KB)
  int w = tid >> 6, lane = tid & 63;
  const u16* srcA = Xb + (size_t)(rp * 64) * NPIX;
  const u16* srcB = Xb + (size_t)(cp * 128) * NPIX;
  // staging: w0 -> A rows 0-31, w1 -> A rows 32-63, w2 -> B rows 0-63, w3 -> B 64-127
  f32x4 acc[4][2];
  #pragma unroll
  for (int t = 0; t < 4; ++t)
    #pragma unroll
    for (int u = 0; u < 2; ++u) acc[t][u] = (f32x4)(0.f);

  #define STAGE_G(buf, k0)                                                   \
    if (w == 0)      { stage16_32(srcA, NPIX, 0, k0, As[buf], lane);         \
                       stage16_32(srcA, NPIX, 16, k0, As[buf], lane); }      \
    else if (w == 1) { stage16_32(srcA, NPIX, 32, k0, As[buf], lane);        \
                       stage16_32(srcA, NPIX, 48, k0, As[buf], lane); }      \
    else if (w == 2) { stage16_32(srcB, NPIX, 0, k0, Bs[buf], lane);         \
                       stage16_32(srcB, NPIX, 16, k0, Bs[buf], lane);        \
                       stage16_32(srcB, NPIX, 32, k0, Bs[buf], lane);        \
                       stage16_32(srcB, NPIX, 48, k0, Bs[buf], lane); }      \
    else             { stage16_32(srcB, NPIX, 64, k0, Bs[buf], lane);        \
                       stage16_32(srcB, NPIX, 80, k0, Bs[buf], lane);        \
                       stage16_32(srcB, NPIX, 96, k0, Bs[buf], lane);        \
                       stage16_32(srcB, NPIX, 112, k0, Bs[buf], lane); }

  STAGE_G(0, kc * 1024);
  __syncthreads();

  for (int st = 0; st < 32; ++st) {
    int cur = st & 1;
    if (st < 31) {
      int k0n = kc * 1024 + (st + 1) * 32;
      STAGE_G(cur ^ 1, k0n);
    }
    int cl = lane >> 4;
    bf16x8 a[4], bb[2];
    #pragma unroll
    for (int t = 0; t < 4; ++t) a[t] = fragld32(As[cur], t * 16 + (lane & 15), cl);
    #pragma unroll
    for (int u = 0; u < 2; ++u) bb[u] = fragld32(Bs[cur], w * 32 + u * 16 + (lane & 15), cl);
    #pragma unroll
    for (int t = 0; t < 4; ++t)
      #pragma unroll
      for (int u = 0; u < 2; ++u)
        acc[t][u] = __builtin_amdgcn_mfma_f32_16x16x32_bf16(a[t], bb[u], acc[t][u], 0, 0, 0);
    __syncthreads();
  }
  #undef STAGE_G
  // tile-local store: Gp[((b*16+kc)*32 + rp*4 + cp)][64][128]
  size_t tbase = ((size_t)(b * 16 + kc) * 32 + rp * 4 + cp) * 8192;
  #pragma unroll
  for (int t = 0; t < 4; ++t) {
    int row0 = t * 16 + (lane >> 4) * 4;
    #pragma unroll
    for (int u = 0; u < 2; ++u) {
      int col = w * 32 + u * 16 + (lane & 15);
      #pragma unroll
      for (int r4 = 0; r4 < 4; ++r4)
        Gp[tbase + (size_t)(row0 + r4) * 128 + col] = acc[t][u][r4];
    }
  }
}

// ================= reduce partials + cov = (G - s s^T/N)/(N-1) + eps I ; rowsum |.|
__global__ __launch_bounds__(256) void gram_reduce(const float* __restrict__ Gp,
                                                   const float* __restrict__ sums,
                                                   float* __restrict__ cov,
                                                   float* __restrict__ rowsum) {
  int idx = blockIdx.x * 256 + threadIdx.x;   // 0 .. 2*MS-1
  int b = idx >> 18;
  int ij = idx & (MS - 1);
  int i = ij >> 9, j = ij & 511;
  int tile = (i >> 6) * 4 + (j >> 7);
  int lij = ((i & 63) << 7) | (j & 127);
  size_t base = ((size_t)(b * 16) * 32 + tile) * 8192 + lij;
  float g = 0.f;
  #pragma unroll
  for (int kc = 0; kc < 16; ++kc)
    g += Gp[base + (size_t)kc * (32 * 8192)];
  const float* s = sums + b * CCH;
  float v = (g - s[i] * s[j] * (1.f / (float)NPIX)) * (1.f / (float)(NPIX - 1));
  if (i == j) v += 1e-8f;
  cov[idx] = v;
  __shared__ float red[256];
  int t = threadIdx.x;
  red[t] = fabsf(v);
  __syncthreads();
  for (int st = 128; st > 0; st >>= 1) {
    if (t < st) red[t] += red[t + st];
    __syncthreads();
  }
  if (t == 0) atomicAdd(&rowsum[b * CCH + i], red[0]);
}

// ================= NS init (+ fused norm/coef): An split; Z0 = (c/2)(3I-Â), c^2=2
__global__ __launch_bounds__(256) void nsinit_k(const float* __restrict__ cov,
                                                const float* __restrict__ rowsum,
                                                float* __restrict__ snorm,
                                                float* __restrict__ coef,
                                                u16* __restrict__ Anh,
                                                u16* __restrict__ Anl,
                                                u16* __restrict__ Z0) {
  __shared__ float red[256];
  int tid = threadIdx.x, blk = blockIdx.x;
  float m = fmaxf(rowsum[tid], rowsum[tid + 256]);
  red[tid] = m; __syncthreads();
  for (int s = 128; s > 0; s >>= 1) {
    if (tid < s) red[tid] = fmaxf(red[tid], red[tid + s]);
    __syncthreads();
  }
  float snc = red[0]; __syncthreads();
  m = fmaxf(rowsum[512 + tid], rowsum[768 + tid]);
  red[tid] = m; __syncthreads();
  for (int s = 128; s > 0; s >>= 1) {
    if (tid < s) red[tid] = fmaxf(red[tid], red[tid + s]);
    __syncthreads();
  }
  float sns = red[0];
  if (blk == 0 && tid == 0) {
    snorm[0] = snc; snorm[1] = sns;
    coef[0] = 0.8f * sqrtf(sns / snc);
  }
  int idx = blk * 256 + tid;                 // 0 .. 2*MS-1 (grid 2048)
  int b = idx >> 18;
  int ij = idx & (MS - 1);
  int diag = (ij >> 9) == (ij & 511);
  float av = cov[idx] * (b ? 1.f / sns : 1.f / snc);
  u16 hi = f2bf(av);
  Anh[idx] = hi;
  Anl[idx] = f2bf(av - b2f(hi));
  float t0 = (diag ? 3.f - av : -av) * 0.70710678f;   // boosted first step
  Z0[idx] = f2bf(t0);
}

// ================= plain bf16 NS matmul, 32x64 tiles (2x fill), Kt=128 dbuf:
// D = diag*I + scale*(A @ B^T).  Grid (8 bj, 16 bi, z).
struct MM16 {
  const u16* A[4];
  const u16* B[4];
  void* D[4];
  float scale, diag;
  int outFp32;
};

__global__ __launch_bounds__(256) void mm16_k(MM16 args) {
  int z = blockIdx.z;
  const u16* __restrict__ A = args.A[z];
  const u16* __restrict__ B = args.B[z];
  int bi = blockIdx.y, bj = blockIdx.x;   // bi: 32-row tile (0..15), bj: 64-col (0..7)
  __shared__ u16 As[2][32 * 128];    // 2 x 8 KB
  __shared__ u16 Bs[2][64 * 128];    // 2 x 16 KB  (total 48 KB)
  int tid = threadIdx.x, w = tid >> 6, lane = tid & 63;
  int qm = w & 1, qn = w >> 1;
  const u16* ssrc = (w < 2) ? A + (size_t)(bi * 32) * CCH
                            : B + (size_t)(bj * 64) * CCH;
  int rbase = (w < 2) ? (w & 1) * 16 : (w & 1) * 32;
  f32x4 acc[2];
  acc[0] = (f32x4)(0.f); acc[1] = (f32x4)(0.f);

  if (w < 2) {
    #pragma unroll
    for (int i = 0; i < 4; ++i) stage4(ssrc, CCH, rbase + i * 4, 0, As[0], lane);
  } else {
    #pragma unroll
    for (int i = 0; i < 8; ++i) stage4(ssrc, CCH, rbase + i * 4, 0, Bs[0], lane);
  }
  __syncthreads();

  for (int st = 0; st < 4; ++st) {
    int cur = st & 1;
    if (st < 3) {
      int k0 = (st + 1) * 128;
      if (w < 2) {
        #pragma unroll
        for (int i = 0; i < 4; ++i) stage4(ssrc, CCH, rbase + i * 4, k0, As[cur ^ 1], lane);
      } else {
        #pragma unroll
        for (int i = 0; i < 8; ++i) stage4(ssrc, CCH, rbase + i * 4, k0, Bs[cur ^ 1], lane);
      }
    }
    #pragma unroll
    for (int s = 0; s < 4; ++s) {
      int cl = s * 4 + (lane >> 4);
      bf16x8 a = fragld(As[cur], qm * 16 + (lane & 15), cl);
      bf16x8 b0 = fragld(Bs[cur], qn * 32 + (lane & 15), cl);
      bf16x8 b1 = fragld(Bs[cur], qn * 32 + 16 + (lane & 15), cl);
      acc[0] = __builtin_amdgcn_mfma_f32_16x16x32_bf16(a, b0, acc[0], 0, 0, 0);
      acc[1] = __builtin_amdgcn_mfma_f32_16x16x32_bf16(a, b1, acc[1], 0, 0, 0);
    }
    __syncthreads();
  }
  float sc = args.scale;
  int row0 = bi * 32 + qm * 16 + (lane >> 4) * 4;
  #pragma unroll
  for (int u = 0; u < 2; ++u) {
    int col = bj * 64 + qn * 32 + u * 16 + (lane & 15);
    #pragma unroll
    for (int r4 = 0; r4 < 4; ++r4) {
      float v = sc * acc[u][r4];
      if (row0 + r4 == col) v += args.diag;
      size_t o = (size_t)(row0 + r4) * CCH + col;
      if (args.outFp32) ((float*)args.D[z])[o] = v;
      else ((u16*)args.D[z])[o] = f2bf(v);
    }
  }
}

// ================= symmetrize + split fp32 -> hi/lo bf16
__global__ __launch_bounds__(256) void symsplit_k(const float* __restrict__ src,
                                                  u16* __restrict__ hi,
                                                  u16* __restrict__ lo) {
  int b = blockIdx.y;
  int ij = blockIdx.x * 256 + threadIdx.x;   // 0..MS-1
  int i = ij >> 9, j = ij & 511;
  size_t base = (size_t)b * MS;
  float v = 0.5f * (src[base + ij] + src[base + (size_t)j * CCH + i]);
  u16 h = f2bf(v);
  hi[base + ij] = h;
  lo[base + ij] = f2bf(v - b2f(h));
}

// ================= split-bf16 matmul, 32x64 tiles (2x fill), Kt=64 dbuf.
struct MMS {
  const u16 *Ah[4], *Al[4], *Bh[4], *Bl[4];
  const u16 *Eh[4], *El[4];
  u16 *Dh[4], *Dl[4];
  float *D32[4];
  u16 *Db[4];
  float scale, beta;
  const float* coefPtr;
};

__global__ __launch_bounds__(256) void mmsplit_k(MMS args) {
  int z = blockIdx.z;
  int bi = blockIdx.y, bj = blockIdx.x;   // bi: 32-row (0..15), bj: 64-col (0..7)
  __shared__ u16 Ash[2][32 * 64], Asl[2][32 * 64];   // 4 x 4 KB
  __shared__ u16 Bsh[2][64 * 64], Bsl[2][64 * 64];   // 4 x 8 KB  (total 48 KB)
  int tid = threadIdx.x, w = tid >> 6, lane = tid & 63;
  int qm = w & 1, qn = w >> 1;
  const u16* sp = (w == 0) ? args.Ah[z] : (w == 1) ? args.Al[z]
                : (w == 2) ? args.Bh[z] : args.Bl[z];
  const u16* ssrc = sp + (size_t)(((w < 2) ? bi * 32 : bj * 64)) * CCH;
  u16* sd0 = (w == 0) ? Ash[0] : (w == 1) ? Asl[0] : (w == 2) ? Bsh[0] : Bsl[0];
  u16* sd1 = (w == 0) ? Ash[1] : (w == 1) ? Asl[1] : (w == 2) ? Bsh[1] : Bsl[1];
  int nst = (w < 2) ? 4 : 8;
  f32x4 acc[2];
  acc[0] = (f32x4)(0.f); acc[1] = (f32x4)(0.f);

  for (int i = 0; i < nst; ++i)
    stage8_64(ssrc, CCH, i * 8, 0, sd0, lane);
  __syncthreads();

  for (int st = 0; st < 8; ++st) {
    int cur = st & 1;
    if (st < 7) {
      u16* sdn = cur ? sd0 : sd1;
      for (int i = 0; i < nst; ++i)
        stage8_64(ssrc, CCH, i * 8, (st + 1) * 64, sdn, lane);
    }
    #pragma unroll
    for (int s = 0; s < 2; ++s) {
      int cl = s * 4 + (lane >> 4);
      int arow = qm * 16 + (lane & 15);
      bf16x8 ah = fragld64(Ash[cur], arow, cl);
      bf16x8 al = fragld64(Asl[cur], arow, cl);
      bf16x8 bh[2], bl[2];
      #pragma unroll
      for (int u = 0; u < 2; ++u) {
        int brow = qn * 32 + u * 16 + (lane & 15);
        bh[u] = fragld64(Bsh[cur], brow, cl);
        bl[u] = fragld64(Bsl[cur], brow, cl);
      }
      #pragma unroll
      for (int u = 0; u < 2; ++u) {
        acc[u] = __builtin_amdgcn_mfma_f32_16x16x32_bf16(ah, bh[u], acc[u], 0, 0, 0);
        acc[u] = __builtin_amdgcn_mfma_f32_16x16x32_bf16(ah, bl[u], acc[u], 0, 0, 0);
        acc[u] = __builtin_amdgcn_mfma_f32_16x16x32_bf16(al, bh[u], acc[u], 0, 0, 0);
      }
    }
    __syncthreads();
  }
  float sc = args.scale;
  if (args.coefPtr) sc *= *args.coefPtr;
  int row0 = bi * 32 + qm * 16 + (lane >> 4) * 4;
  #pragma unroll
  for (int u = 0; u < 2; ++u) {
    int col = bj * 64 + qn * 32 + u * 16 + (lane & 15);
    #pragma unroll
    for (int r4 = 0; r4 < 4; ++r4) {
      size_t o = (size_t)(row0 + r4) * CCH + col;
      float v = sc * acc[u][r4];
      if (args.beta != 0.f) v += args.beta * (b2f(args.Eh[z][o]) + b2f(args.El[z][o]));
      if (args.D32[z]) args.D32[z][o] = v;
      if (args.Dh[z]) {
        u16 h = f2bf(v);
        args.Dh[z][o] = h;
        args.Dl[z][o] = f2bf(v - b2f(h));
      }
      if (args.Db[z]) args.Db[z][o] = f2bf(v);
    }
  }
}

// ================= mconst[c] = (0.8*ssum[c] - (M @ csum)[c]) / N
__global__ __launch_bounds__(256) void mconst_k(const u16* __restrict__ Mb,
                                                const float* __restrict__ sums,
                                                float* __restrict__ mconst) {
  int c = blockIdx.x * 8 + (threadIdx.x >> 5);   // grid 64
  int l = threadIdx.x & 31;
  float s = 0.f;
  #pragma unroll
  for (int k = 0; k < 16; ++k) {
    int j = l + 32 * k;
    s += b2f(Mb[(size_t)c * CCH + j]) * sums[j];
  }
  s += __shfl_down(s, 16, 32);
  s += __shfl_down(s, 8, 32);
  s += __shfl_down(s, 4, 32);
  s += __shfl_down(s, 2, 32);
  s += __shfl_down(s, 1, 32);
  if (l == 0) mconst[c] = (0.8f * sums[512 + c] - s) * (1.f / (float)NPIX);
}

// ================= apply: out = fcb @ M^T + mconst + 0.2 X   (128-tiles, Kt=64 dbuf)
__global__ __launch_bounds__(256) void apply_mfma(const u16* __restrict__ fcb,
                                                  const u16* __restrict__ Mb,
                                                  const float* __restrict__ mconst,
                                                  const float* __restrict__ X,
                                                  float* __restrict__ out) {
  int bi = blockIdx.y;    // n tile (0..127)
  int bj = blockIdx.x;    // c tile (0..3)
  __shared__ u16 As[2][128 * 64];    // 2 x 16 KB
  __shared__ u16 Bs[2][128 * 64];    // 2 x 16 KB
  int tid = threadIdx.x, w = tid >> 6, lane = tid & 63;
  int qm = w & 1, qn = w >> 1;
  const u16* ssrc = (w < 2) ? fcb + (size_t)(bi * 128) * CCH
                            : Mb + (size_t)(bj * 128) * CCH;
  int rbase = (w & 1) * 64;
  f32x4 acc[4][4];
  #pragma unroll
  for (int t = 0; t < 4; ++t)
    #pragma unroll
    for (int u = 0; u < 4; ++u) acc[t][u] = (f32x4)(0.f);

  #pragma unroll
  for (int i = 0; i < 8; ++i)
    stage8_64(ssrc, CCH, rbase + i * 8, 0, (w < 2) ? As[0] : Bs[0], lane);
  __syncthreads();

  for (int st = 0; st < 8; ++st) {
    int cur = st & 1;
    if (st < 7) {
      #pragma unroll
      for (int i = 0; i < 8; ++i)
        stage8_64(ssrc, CCH, rbase + i * 8, (st + 1) * 64,
                  (w < 2) ? As[cur ^ 1] : Bs[cur ^ 1], lane);
    }
    #pragma unroll
    for (int s = 0; s < 2; ++s) {
      int cl = s * 4 + (lane >> 4);
      bf16x8 a[4], bb[4];
      #pragma unroll
      for (int t = 0; t < 4; ++t) a[t] = fragld64(As[cur], qm * 64 + t * 16 + (lane & 15), cl);
      #pragma unroll
      for (int u = 0; u < 4; ++u) bb[u] = fragld64(Bs[cur], qn * 64 + u * 16 + (lane & 15), cl);
      #pragma unroll
      for (int t = 0; t < 4; ++t)
        #pragma unroll
        for (int u = 0; u < 4; ++u)
          acc[t][u] = __builtin_amdgcn_mfma_f32_16x16x32_bf16(a[t], bb[u], acc[t][u], 0, 0, 0);
    }
    __syncthreads();
  }
  #pragma unroll
  for (int t = 0; t < 4; ++t) {
    int row0 = bi * 128 + qm * 64 + t * 16 + (lane >> 4) * 4;
    #pragma unroll
    for (int u = 0; u < 4; ++u) {
      int col = bj * 128 + qn * 64 + u * 16 + (lane & 15);
      float cst = mconst[col];
      #pragma unroll
      for (int r4 = 0; r4 < 4; ++r4) {
        size_t o = (size_t)(row0 + r4) * CCH + col;
        out[o] = acc[t][u][r4] + cst + 0.2f * X[o];
      }
    }
  }
}

// ================================================================ launcher
extern "C" void kernel_launch(void* const* d_in, const int* in_sizes, int n_in,
                              void* d_out, int out_size, void* d_ws, size_t ws_size,
                              hipStream_t stream) {
  const float* Xc = (const float*)d_in[0];
  const float* Xs = (const float*)d_in[1];
  float* out = (float*)d_out;

  float* f = (float*)d_ws;
  float* sums   = f;                     // 1024 (written by gram_part fold)
  float* rowsum = f + 1024;              // 1024
  float* s16    = f + 2048;              // 16 buckets x 1024 = 16384 (zeroed)
  float* cov    = f + 2048 + 2 * MS;     // 2*MS
  float* snorm  = cov + 2 * MS;          // 8
  float* coef   = snorm + 8;             // 8
  float* mconst = coef + 8;              // 512
  float* Zf     = mconst + 512;          // 2*MS (fp32, reused for Zr)

  // Gram split-K partials live in d_out (dead until apply_mfma):
  // 2 b x 16 kc x 32 tiles x 64x128 fp32 = 32 MiB exactly.
  float* Gp = (float*)d_out;

  u16* h   = (u16*)(Zf + 2 * MS);
  u16* fct = h;                          // 2*512*16384 u16 (dead after gram)
  u16* fcb = h + (size_t)2 * CCH * NPIX; // 16384*512 u16
  const size_t B2 = 2 * MS;
  u16* Anh  = fct + 0 * B2;
  u16* Anl  = fct + 1 * B2;
  u16* Y1   = fct + 2 * B2;
  u16* Ya   = fct + 3 * B2;
  u16* Z0   = fct + 4 * B2;
  u16* Z1   = fct + 5 * B2;
  u16* Tb   = fct + 6 * B2;
  u16* Zfsh = fct + 7 * B2;
  u16* Zfsl = fct + 8 * B2;
  u16* Ph   = fct + 9 * B2;
  u16* Pl   = fct + 10 * B2;
  u16* Qh   = fct + 11 * B2;
  u16* Ql   = fct + 12 * B2;
  u16* Zrsh = fct + 13 * B2;
  u16* Zrsl = fct + 14 * B2;
  u16* W2h  = fct + 15 * B2;
  u16* W2l  = W2h + MS;
  u16* Mb   = W2l + MS;

  // zero: sums + rowsum + 16-bucket colsum partials
  hipMemsetAsync(d_ws, 0, (2048 + 16384) * sizeof(float), stream);

  prep_k<<<dim3(256, 8, 2), 256, 0, stream>>>(Xc, Xs, s16, fct, fcb);
  gram_part<<<dim3(16, 32, 2), 256, 0, stream>>>(fct, Gp, s16, sums);
  gram_reduce<<<2048, 256, 0, stream>>>(Gp, sums, cov, rowsum);
  nsinit_k<<<2048, 256, 0, stream>>>(cov, rowsum, snorm, coef, Anh, Anl, Z0);

  // NS: boosted first step (in nsinit) + 2 full iterations + final Z-update
  {
    MM16 y1{};
    y1.A[0] = Anh;      y1.B[0] = Z0;      y1.D[0] = Y1;
    y1.A[1] = Anh + MS; y1.B[1] = Z0 + MS; y1.D[1] = Y1 + MS;
    y1.scale = 1.f; y1.diag = 0.f; y1.outFp32 = 0;
    mm16_k<<<dim3(8, 16, 2), 256, 0, stream>>>(y1);
  }
  {
    MM16 t{};   // T0 = 3I - Z0 @ Y1
    t.A[0] = Z0;      t.B[0] = Y1;      t.D[0] = Tb;
    t.A[1] = Z0 + MS; t.B[1] = Y1 + MS; t.D[1] = Tb + MS;
    t.scale = -1.f; t.diag = 3.f; t.outFp32 = 0;
    mm16_k<<<dim3(8, 16, 2), 256, 0, stream>>>(t);
  }
  {
    MM16 yz{};  // Ya = Y1@T0/2 ; Z1 = T0@Z0/2
    yz.A[0] = Y1;      yz.B[0] = Tb;      yz.D[0] = Ya;
    yz.A[1] = Y1 + MS; yz.B[1] = Tb + MS; yz.D[1] = Ya + MS;
    yz.A[2] = Tb;      yz.B[2] = Z0;      yz.D[2] = Z1;
    yz.A[3] = Tb + MS; yz.B[3] = Z0 + MS; yz.D[3] = Z1 + MS;
    yz.scale = 0.5f; yz.diag = 0.f; yz.outFp32 = 0;
    mm16_k<<<dim3(8, 16, 4), 256, 0, stream>>>(yz);
  }
  {
    MM16 t{};   // T1 = 3I - Z1 @ Ya
    t.A[0] = Z1;      t.B[0] = Ya;      t.D[0] = Tb;
    t.A[1] = Z1 + MS; t.B[1] = Ya + MS; t.D[1] = Tb + MS;
    t.scale = -1.f; t.diag = 3.f; t.outFp32 = 0;
    mm16_k<<<dim3(8, 16, 2), 256, 0, stream>>>(t);
  }
  {
    MM16 yz{};  // Y1 = Ya@T1/2 ; Z0 = T1@Z1/2
    yz.A[0] = Ya;      yz.B[0] = Tb;      yz.D[0] = Y1;
    yz.A[1] = Ya + MS; yz.B[1] = Tb + MS; yz.D[1] = Y1 + MS;
    yz.A[2] = Tb;      yz.B[2] = Z1;      yz.D[2] = Z0;
    yz.A[3] = Tb + MS; yz.B[3] = Z1 + MS; yz.D[3] = Z0 + MS;
    yz.scale = 0.5f; yz.diag = 0.f; yz.outFp32 = 0;
    mm16_k<<<dim3(8, 16, 4), 256, 0, stream>>>(yz);
  }
  {
    MM16 t{};   // T2 = 3I - Z0 @ Y1
    t.A[0] = Z0;      t.B[0] = Y1;      t.D[0] = Tb;
    t.A[1] = Z0 + MS; t.B[1] = Y1 + MS; t.D[1] = Tb + MS;
    t.scale = -1.f; t.diag = 3.f; t.outFp32 = 0;
    mm16_k<<<dim3(8, 16, 2), 256, 0, stream>>>(t);
  }
  {
    MM16 zf{};  // Zf = T2 @ Z0 / 2  (fp32)
    zf.A[0] = Tb;      zf.B[0] = Z0;      zf.D[0] = Zf;
    zf.A[1] = Tb + MS; zf.B[1] = Z0 + MS; zf.D[1] = Zf + MS;
    zf.scale = 0.5f; zf.diag = 0.f; zf.outFp32 = 1;
    mm16_k<<<dim3(8, 16, 2), 256, 0, stream>>>(zf);
  }

  // symmetrize+split Zf
  symsplit_k<<<dim3(1024, 2), 256, 0, stream>>>(Zf, Zfsh, Zfsl);

  // P_b = Zfs_b @ An_b ; Q_b = Zfs_b @ Zfs_b
  MMS pq{};
  for (int b = 0; b < 2; ++b) {
    pq.Ah[b] = Zfsh + b * MS; pq.Al[b] = Zfsl + b * MS;
    pq.Bh[b] = Anh + b * MS;  pq.Bl[b] = Anl + b * MS;
    pq.Dh[b] = Ph + b * MS;   pq.Dl[b] = Pl + b * MS;
    pq.Ah[2 + b] = Zfsh + b * MS; pq.Al[2 + b] = Zfsl + b * MS;
    pq.Bh[2 + b] = Zfsh + b * MS; pq.Bl[2 + b] = Zfsl + b * MS;
    pq.Dh[2 + b] = Qh + b * MS;   pq.Dl[2 + b] = Ql + b * MS;
  }
  pq.scale = 1.f;
  mmsplit_k<<<dim3(8, 16, 4), 256, 0, stream>>>(pq);

  // Zr_b = 1.5 Zfs_b - 0.5 P_b @ Q_b  (fp32 out into Zf)
  MMS zr{};
  for (int b = 0; b < 2; ++b) {
    zr.Ah[b] = Ph + b * MS;   zr.Al[b] = Pl + b * MS;
    zr.Bh[b] = Qh + b * MS;   zr.Bl[b] = Ql + b * MS;
    zr.Eh[b] = Zfsh + b * MS; zr.El[b] = Zfsl + b * MS;
    zr.D32[b] = Zf + b * MS;
  }
  zr.scale = -0.5f; zr.beta = 1.5f;
  mmsplit_k<<<dim3(8, 16, 2), 256, 0, stream>>>(zr);

  // symmetrize+split Zr
  symsplit_k<<<dim3(1024, 2), 256, 0, stream>>>(Zf, Zrsh, Zrsl);

  // W2 = An_s @ Zrs_s (split out)
  MMS wv{};
  wv.Ah[0] = Anh + MS;  wv.Al[0] = Anl + MS;
  wv.Bh[0] = Zrsh + MS; wv.Bl[0] = Zrsl + MS;
  wv.Dh[0] = W2h; wv.Dl[0] = W2l;
  wv.scale = 1.f;
  mmsplit_k<<<dim3(8, 16, 1), 256, 0, stream>>>(wv);

  // M = coef * W2 @ Zrs_c (bf16 out)
  MMS mv{};
  mv.Ah[0] = W2h;  mv.Al[0] = W2l;
  mv.Bh[0] = Zrsh; mv.Bl[0] = Zrsl;
  mv.Db[0] = Mb;
  mv.scale = 1.f; mv.coefPtr = coef;
  mmsplit_k<<<dim3(8, 16, 1), 256, 0, stream>>>(mv);

  mconst_k<<<64, 256, 0, stream>>>(Mb, sums, mconst);
  apply_mfma<<<dim3(4, 128), 256, 0, stream>>>(fcb, Mb, mconst, Xc, out);
}

// Round 10
// 268.575 us; speedup vs baseline: 1.0163x; 1.0163x over previous
//
#include <hip/hip_runtime.h>
#include <math.h>

#define NPIX 16384      // H*W
#define CCH  512        // channels
#define MS   262144     // 512*512

typedef unsigned short u16;
typedef unsigned int u32;
typedef __attribute__((ext_vector_type(8))) short bf16x8;   // 8 bf16 = 4 VGPR
typedef __attribute__((ext_vector_type(4))) float f32x4;

__device__ __forceinline__ u16 f2bf(float f) {
  u32 u = __builtin_bit_cast(u32, f);
  u += 0x7fffu + ((u >> 16) & 1u);    // round-to-nearest-even
  return (u16)(u >> 16);
}
__device__ __forceinline__ float b2f(u16 h) {
  u32 u = ((u32)h) << 16;
  return __builtin_bit_cast(float, u);
}

typedef const __attribute__((address_space(1))) u32* gp_t;
typedef __attribute__((address_space(3))) u32* lp_t;
__device__ __forceinline__ void gl_lds16(const void* g, void* l) {
  __builtin_amdgcn_global_load_lds((gp_t)g, (lp_t)l, 16, 0, 0);
}

// ---- Kt=128 staged tile, XOR chunk swizzle (LDS row = 128 bf16 = 16x16B chunks)
__device__ __forceinline__ void stage4(const u16* tile, size_t stride, int rl,
                                       int k0, u16* lds, int lane) {
  int lr = lane >> 4;                               // 4 rows per instruction
  int cg2 = (lane & 15) ^ ((rl + lr) & 15);         // swizzled global chunk
  gl_lds16(tile + (size_t)(rl + lr) * stride + k0 + cg2 * 8,
           lds + (size_t)rl * 128);
}
__device__ __forceinline__ bf16x8 fragld(const u16* lds, int row, int cl) {
  return *(const bf16x8*)&lds[(size_t)row * 128 + (size_t)((cl ^ (row & 15)) << 3)];
}

// ---- Kt=64 variants (LDS row = 64 bf16 = 8x16B chunks); 8 rows per gl_lds16
__device__ __forceinline__ void stage8_64(const u16* tile, size_t stride, int rl,
                                          int k0, u16* lds, int lane) {
  int lr = lane >> 3;                               // 8 rows per instruction
  int cg2 = (lane & 7) ^ ((rl + lr) & 7);           // swizzled global chunk
  gl_lds16(tile + (size_t)(rl + lr) * stride + k0 + cg2 * 8,
           lds + (size_t)rl * 64);
}
__device__ __forceinline__ bf16x8 fragld64(const u16* lds, int row, int cl) {
  return *(const bf16x8*)&lds[(size_t)row * 64 + (size_t)((cl ^ (row & 7)) << 3)];
}

// ================= prep: one pass over X -> bucketed colsum partials,
// fct (bf16 [c][n]), fcb (bf16 [n][c]).
__global__ __launch_bounds__(256) void prep_k(const float* __restrict__ Xc,
                                              const float* __restrict__ Xs,
                                              float* __restrict__ s16,
                                              u16* __restrict__ fct,
                                              u16* __restrict__ fcb) {
  int b = blockIdx.z;
  const float* X = b ? Xs : Xc;
  u16* outT = fct + (size_t)b * ((size_t)CCH * NPIX);
  __shared__ float T[64][65];
  __shared__ float red2[64][4];
  int n0 = blockIdx.x * 64, c0 = blockIdx.y * 64;
  int t = threadIdx.x;
  int cr = t & 15, nr = t >> 4;
  #pragma unroll
  for (int rr = 0; rr < 4; ++rr) {
    int n = nr + rr * 16;
    float4 v = *(const float4*)&X[(size_t)(n0 + n) * CCH + c0 + cr * 4];
    T[n][cr * 4 + 0] = v.x;
    T[n][cr * 4 + 1] = v.y;
    T[n][cr * 4 + 2] = v.z;
    T[n][cr * 4 + 3] = v.w;
    if (b == 0) {
      ushort4 q;
      q.x = f2bf(v.x); q.y = f2bf(v.y); q.z = f2bf(v.z); q.w = f2bf(v.w);
      *(ushort4*)&fcb[(size_t)(n0 + n) * CCH + c0 + cr * 4] = q;
    }
  }
  __syncthreads();
  int cl = t >> 2, np = (t & 3) * 16;
  size_t obase = (size_t)(c0 + cl) * NPIX + n0 + np;
  float s = 0.f;
  u16 ov[16];
  #pragma unroll
  for (int i = 0; i < 16; i += 4) {
    float v0 = T[np + i + 0][cl], v1 = T[np + i + 1][cl];
    float v2 = T[np + i + 2][cl], v3 = T[np + i + 3][cl];
    s += v0 + v1 + v2 + v3;
    ov[i + 0] = f2bf(v0); ov[i + 1] = f2bf(v1);
    ov[i + 2] = f2bf(v2); ov[i + 3] = f2bf(v3);
  }
  *(bf16x8*)&outT[obase + 0] = *(bf16x8*)&ov[0];   // 16B stores
  *(bf16x8*)&outT[obase + 8] = *(bf16x8*)&ov[8];
  red2[cl][t & 3] = s;
  __syncthreads();
  if (t < 64) {
    float cs = red2[t][0] + red2[t][1] + red2[t][2] + red2[t][3];
    atomicAdd(&s16[(blockIdx.x & 15) * 1024 + b * CCH + c0 + t], cs);
  }
}

// ================= Gram partials: 16 pairs x 16 kc x 2 batches = 512 blocks = 2/CU
__global__ __launch_bounds__(256, 2) void gram_part(const u16* __restrict__ fct,
                                                    float* __restrict__ Gp,
                                                    const float* __restrict__ s16,
                                                    float* __restrict__ sums) {
  int kc = blockIdx.x;               // 0..15, K chunk of 1024
  int pair = blockIdx.y;             // 0..15
  int b = blockIdx.z;
  int tid = threadIdx.x;
  if (kc == 0 && pair == 0) {
    #pragma unroll
    for (int c = tid; c < CCH; c += 256) {
      float s = 0.f;
      #pragma unroll
      for (int k = 0; k < 16; ++k) s += s16[k * 1024 + b * CCH + c];
      sums[b * CCH + c] = s;
    }
  }
  int bi = pair >> 2, bj = pair & 3;
  const u16* Xb = fct + (size_t)b * ((size_t)CCH * NPIX);
  __shared__ u16 As[2][128 * 64];    // 2 x 16 KB
  __shared__ u16 Bs[2][128 * 64];    // 2 x 16 KB
  int w = tid >> 6, lane = tid & 63;
  int qm = w & 1, qn = w >> 1;
  const u16* ssrc = (w < 2) ? Xb + (size_t)(bi * 128) * NPIX
                            : Xb + (size_t)(bj * 128) * NPIX;
  int rbase = (w & 1) * 64;
  f32x4 acc[4][4];
  #pragma unroll
  for (int t = 0; t < 4; ++t)
    #pragma unroll
    for (int u = 0; u < 4; ++u) acc[t][u] = (f32x4)(0.f);

  #pragma unroll
  for (int i = 0; i < 8; ++i)
    stage8_64(ssrc, NPIX, rbase + i * 8, kc * 1024, (w < 2) ? As[0] : Bs[0], lane);
  __syncthreads();

  for (int st = 0; st < 16; ++st) {
    int cur = st & 1;
    if (st < 15) {
      int k0n = kc * 1024 + (st + 1) * 64;
      #pragma unroll
      for (int i = 0; i < 8; ++i)
        stage8_64(ssrc, NPIX, rbase + i * 8, k0n,
                  (w < 2) ? As[cur ^ 1] : Bs[cur ^ 1], lane);
    }
    #pragma unroll
    for (int s = 0; s < 2; ++s) {
      int cl = s * 4 + (lane >> 4);
      bf16x8 a[4], bb[4];
      #pragma unroll
      for (int t = 0; t < 4; ++t) a[t] = fragld64(As[cur], qm * 64 + t * 16 + (lane & 15), cl);
      #pragma unroll
      for (int u = 0; u < 4; ++u) bb[u] = fragld64(Bs[cur], qn * 64 + u * 16 + (lane & 15), cl);
      #pragma unroll
      for (int t = 0; t < 4; ++t)
        #pragma unroll
        for (int u = 0; u < 4; ++u)
          acc[t][u] = __builtin_amdgcn_mfma_f32_16x16x32_bf16(a[t], bb[u], acc[t][u], 0, 0, 0);
    }
    __syncthreads();
  }
  size_t tbase = ((size_t)(b * 16 + kc) * 16 + pair) * 16384;
  #pragma unroll
  for (int t = 0; t < 4; ++t) {
    int row0 = qm * 64 + t * 16 + (lane >> 4) * 4;
    #pragma unroll
    for (int u = 0; u < 4; ++u) {
      int col = qn * 64 + u * 16 + (lane & 15);
      #pragma unroll
      for (int r4 = 0; r4 < 4; ++r4)
        Gp[tbase + (size_t)(row0 + r4) * 128 + col] = acc[t][u][r4];
    }
  }
}

// ================= reduce partials + cov = (G - s s^T/N)/(N-1) + eps I ; rowsum |.|
__global__ __launch_bounds__(256) void gram_reduce(const float* __restrict__ Gp,
                                                   const float* __restrict__ sums,
                                                   float* __restrict__ cov,
                                                   float* __restrict__ rowsum) {
  int idx = blockIdx.x * 256 + threadIdx.x;   // 0 .. 2*MS-1
  int b = idx >> 18;
  int ij = idx & (MS - 1);
  int i = ij >> 9, j = ij & 511;
  int pair = ((i >> 7) << 2) | (j >> 7);
  int lij = ((i & 127) << 7) | (j & 127);
  size_t base = ((size_t)(b * 16) * 16 + pair) * 16384 + lij;
  float g = 0.f;
  #pragma unroll
  for (int kc = 0; kc < 16; ++kc)
    g += Gp[base + (size_t)kc * (16 * 16384)];
  const float* s = sums + b * CCH;
  float v = (g - s[i] * s[j] * (1.f / (float)NPIX)) * (1.f / (float)(NPIX - 1));
  if (i == j) v += 1e-8f;
  cov[idx] = v;
  __shared__ float red[256];
  int t = threadIdx.x;
  red[t] = fabsf(v);
  __syncthreads();
  for (int st = 128; st > 0; st >>= 1) {
    if (t < st) red[t] += red[t + st];
    __syncthreads();
  }
  if (t == 0) atomicAdd(&rowsum[b * CCH + i], red[0]);
}

// ================= NS init (+ fused norm/coef): An split; Z0 = (c/2)(3I-Â), c^2=2
__global__ __launch_bounds__(256) void nsinit_k(const float* __restrict__ cov,
                                                const float* __restrict__ rowsum,
                                                float* __restrict__ snorm,
                                                float* __restrict__ coef,
                                                u16* __restrict__ Anh,
                                                u16* __restrict__ Anl,
                                                u16* __restrict__ Z0) {
  __shared__ float red[256];
  int tid = threadIdx.x, blk = blockIdx.x;
  float m = fmaxf(rowsum[tid], rowsum[tid + 256]);
  red[tid] = m; __syncthreads();
  for (int s = 128; s > 0; s >>= 1) {
    if (tid < s) red[tid] = fmaxf(red[tid], red[tid + s]);
    __syncthreads();
  }
  float snc = red[0]; __syncthreads();
  m = fmaxf(rowsum[512 + tid], rowsum[768 + tid]);
  red[tid] = m; __syncthreads();
  for (int s = 128; s > 0; s >>= 1) {
    if (tid < s) red[tid] = fmaxf(red[tid], red[tid + s]);
    __syncthreads();
  }
  float sns = red[0];
  if (blk == 0 && tid == 0) {
    snorm[0] = snc; snorm[1] = sns;
    coef[0] = 0.8f * sqrtf(sns / snc);
  }
  int idx = blk * 256 + tid;                 // 0 .. 2*MS-1 (grid 2048)
  int b = idx >> 18;
  int ij = idx & (MS - 1);
  int diag = (ij >> 9) == (ij & 511);
  float av = cov[idx] * (b ? 1.f / sns : 1.f / snc);
  u16 hi = f2bf(av);
  Anh[idx] = hi;
  Anl[idx] = f2bf(av - b2f(hi));
  float t0 = (diag ? 3.f - av : -av) * 0.70710678f;   // boosted first step
  Z0[idx] = f2bf(t0);
}

// ================= plain bf16 NS matmul, 32x64 tiles (2x fill), Kt=128 dbuf:
// D = diag*I + scale*(A @ B^T).  Grid (8 bj, 16 bi, z).
struct MM16 {
  const u16* A[4];
  const u16* B[4];
  void* D[4];
  float scale, diag;
  int outFp32;
};

__global__ __launch_bounds__(256) void mm16_k(MM16 args) {
  int z = blockIdx.z;
  const u16* __restrict__ A = args.A[z];
  const u16* __restrict__ B = args.B[z];
  int bi = blockIdx.y, bj = blockIdx.x;   // bi: 32-row tile (0..15), bj: 64-col (0..7)
  __shared__ u16 As[2][32 * 128];    // 2 x 8 KB
  __shared__ u16 Bs[2][64 * 128];    // 2 x 16 KB  (total 48 KB)
  int tid = threadIdx.x, w = tid >> 6, lane = tid & 63;
  int qm = w & 1, qn = w >> 1;
  const u16* ssrc = (w < 2) ? A + (size_t)(bi * 32) * CCH
                            : B + (size_t)(bj * 64) * CCH;
  int rbase = (w < 2) ? (w & 1) * 16 : (w & 1) * 32;
  f32x4 acc[2];
  acc[0] = (f32x4)(0.f); acc[1] = (f32x4)(0.f);

  if (w < 2) {
    #pragma unroll
    for (int i = 0; i < 4; ++i) stage4(ssrc, CCH, rbase + i * 4, 0, As[0], lane);
  } else {
    #pragma unroll
    for (int i = 0; i < 8; ++i) stage4(ssrc, CCH, rbase + i * 4, 0, Bs[0], lane);
  }
  __syncthreads();

  for (int st = 0; st < 4; ++st) {
    int cur = st & 1;
    if (st < 3) {
      int k0 = (st + 1) * 128;
      if (w < 2) {
        #pragma unroll
        for (int i = 0; i < 4; ++i) stage4(ssrc, CCH, rbase + i * 4, k0, As[cur ^ 1], lane);
      } else {
        #pragma unroll
        for (int i = 0; i < 8; ++i) stage4(ssrc, CCH, rbase + i * 4, k0, Bs[cur ^ 1], lane);
      }
    }
    #pragma unroll
    for (int s = 0; s < 4; ++s) {
      int cl = s * 4 + (lane >> 4);
      bf16x8 a = fragld(As[cur], qm * 16 + (lane & 15), cl);
      bf16x8 b0 = fragld(Bs[cur], qn * 32 + (lane & 15), cl);
      bf16x8 b1 = fragld(Bs[cur], qn * 32 + 16 + (lane & 15), cl);
      acc[0] = __builtin_amdgcn_mfma_f32_16x16x32_bf16(a, b0, acc[0], 0, 0, 0);
      acc[1] = __builtin_amdgcn_mfma_f32_16x16x32_bf16(a, b1, acc[1], 0, 0, 0);
    }
    __syncthreads();
  }
  float sc = args.scale;
  int row0 = bi * 32 + qm * 16 + (lane >> 4) * 4;
  #pragma unroll
  for (int u = 0; u < 2; ++u) {
    int col = bj * 64 + qn * 32 + u * 16 + (lane & 15);
    #pragma unroll
    for (int r4 = 0; r4 < 4; ++r4) {
      float v = sc * acc[u][r4];
      if (row0 + r4 == col) v += args.diag;
      size_t o = (size_t)(row0 + r4) * CCH + col;
      if (args.outFp32) ((float*)args.D[z])[o] = v;
      else ((u16*)args.D[z])[o] = f2bf(v);
    }
  }
}

// ================= symmetrize + split fp32 -> hi/lo bf16
__global__ __launch_bounds__(256) void symsplit_k(const float* __restrict__ src,
                                                  u16* __restrict__ hi,
                                                  u16* __restrict__ lo) {
  int b = blockIdx.y;
  int ij = blockIdx.x * 256 + threadIdx.x;   // 0..MS-1
  int i = ij >> 9, j = ij & 511;
  size_t base = (size_t)b * MS;
  float v = 0.5f * (src[base + ij] + src[base + (size_t)j * CCH + i]);
  u16 h = f2bf(v);
  hi[base + ij] = h;
  lo[base + ij] = f2bf(v - b2f(h));
}

// ================= split-bf16 matmul, 32x64 tiles (2x fill), Kt=64 dbuf.
struct MMS {
  const u16 *Ah[4], *Al[4], *Bh[4], *Bl[4];
  const u16 *Eh[4], *El[4];
  u16 *Dh[4], *Dl[4];
  float *D32[4];
  u16 *Db[4];
  float scale, beta;
  const float* coefPtr;
};

__global__ __launch_bounds__(256) void mmsplit_k(MMS args) {
  int z = blockIdx.z;
  int bi = blockIdx.y, bj = blockIdx.x;   // bi: 32-row (0..15), bj: 64-col (0..7)
  __shared__ u16 Ash[2][32 * 64], Asl[2][32 * 64];   // 4 x 4 KB
  __shared__ u16 Bsh[2][64 * 64], Bsl[2][64 * 64];   // 4 x 8 KB  (total 48 KB)
  int tid = threadIdx.x, w = tid >> 6, lane = tid & 63;
  int qm = w & 1, qn = w >> 1;
  const u16* sp = (w == 0) ? args.Ah[z] : (w == 1) ? args.Al[z]
                : (w == 2) ? args.Bh[z] : args.Bl[z];
  const u16* ssrc = sp + (size_t)(((w < 2) ? bi * 32 : bj * 64)) * CCH;
  u16* sd0 = (w == 0) ? Ash[0] : (w == 1) ? Asl[0] : (w == 2) ? Bsh[0] : Bsl[0];
  u16* sd1 = (w == 0) ? Ash[1] : (w == 1) ? Asl[1] : (w == 2) ? Bsh[1] : Bsl[1];
  int nst = (w < 2) ? 4 : 8;
  f32x4 acc[2];
  acc[0] = (f32x4)(0.f); acc[1] = (f32x4)(0.f);

  for (int i = 0; i < nst; ++i)
    stage8_64(ssrc, CCH, i * 8, 0, sd0, lane);
  __syncthreads();

  for (int st = 0; st < 8; ++st) {
    int cur = st & 1;
    if (st < 7) {
      u16* sdn = cur ? sd0 : sd1;
      for (int i = 0; i < nst; ++i)
        stage8_64(ssrc, CCH, i * 8, (st + 1) * 64, sdn, lane);
    }
    #pragma unroll
    for (int s = 0; s < 2; ++s) {
      int cl = s * 4 + (lane >> 4);
      int arow = qm * 16 + (lane & 15);
      bf16x8 ah = fragld64(Ash[cur], arow, cl);
      bf16x8 al = fragld64(Asl[cur], arow, cl);
      bf16x8 bh[2], bl[2];
      #pragma unroll
      for (int u = 0; u < 2; ++u) {
        int brow = qn * 32 + u * 16 + (lane & 15);
        bh[u] = fragld64(Bsh[cur], brow, cl);
        bl[u] = fragld64(Bsl[cur], brow, cl);
      }
      #pragma unroll
      for (int u = 0; u < 2; ++u) {
        acc[u] = __builtin_amdgcn_mfma_f32_16x16x32_bf16(ah, bh[u], acc[u], 0, 0, 0);
        acc[u] = __builtin_amdgcn_mfma_f32_16x16x32_bf16(ah, bl[u], acc[u], 0, 0, 0);
        acc[u] = __builtin_amdgcn_mfma_f32_16x16x32_bf16(al, bh[u], acc[u], 0, 0, 0);
      }
    }
    __syncthreads();
  }
  float sc = args.scale;
  if (args.coefPtr) sc *= *args.coefPtr;
  int row0 = bi * 32 + qm * 16 + (lane >> 4) * 4;
  #pragma unroll
  for (int u = 0; u < 2; ++u) {
    int col = bj * 64 + qn * 32 + u * 16 + (lane & 15);
    #pragma unroll
    for (int r4 = 0; r4 < 4; ++r4) {
      size_t o = (size_t)(row0 + r4) * CCH + col;
      float v = sc * acc[u][r4];
      if (args.beta != 0.f) v += args.beta * (b2f(args.Eh[z][o]) + b2f(args.El[z][o]));
      if (args.D32[z]) args.D32[z][o] = v;
      if (args.Dh[z]) {
        u16 h = f2bf(v);
        args.Dh[z][o] = h;
        args.Dl[z][o] = f2bf(v - b2f(h));
      }
      if (args.Db[z]) args.Db[z][o] = f2bf(v);
    }
  }
}

// ================= mconst[c] = (0.8*ssum[c] - (M @ csum)[c]) / N
__global__ __launch_bounds__(256) void mconst_k(const u16* __restrict__ Mb,
                                                const float* __restrict__ sums,
                                                float* __restrict__ mconst) {
  int c = blockIdx.x * 8 + (threadIdx.x >> 5);   // grid 64
  int l = threadIdx.x & 31;
  float s = 0.f;
  #pragma unroll
  for (int k = 0; k < 16; ++k) {
    int j = l + 32 * k;
    s += b2f(Mb[(size_t)c * CCH + j]) * sums[j];
  }
  s += __shfl_down(s, 16, 32);
  s += __shfl_down(s, 8, 32);
  s += __shfl_down(s, 4, 32);
  s += __shfl_down(s, 2, 32);
  s += __shfl_down(s, 1, 32);
  if (l == 0) mconst[c] = (0.8f * sums[512 + c] - s) * (1.f / (float)NPIX);
}

// ================= apply: out = fcb @ M^T + mconst + 0.2 X   (128-tiles, Kt=64 dbuf)
__global__ __launch_bounds__(256) void apply_mfma(const u16* __restrict__ fcb,
                                                  const u16* __restrict__ Mb,
                                                  const float* __restrict__ mconst,
                                                  const float* __restrict__ X,
                                                  float* __restrict__ out) {
  int bi = blockIdx.y;    // n tile (0..127)
  int bj = blockIdx.x;    // c tile (0..3)
  __shared__ u16 As[2][128 * 64];    // 2 x 16 KB
  __shared__ u16 Bs[2][128 * 64];    // 2 x 16 KB
  int tid = threadIdx.x, w = tid >> 6, lane = tid & 63;
  int qm = w & 1, qn = w >> 1;
  const u16* ssrc = (w < 2) ? fcb + (size_t)(bi * 128) * CCH
                            : Mb + (size_t)(bj * 128) * CCH;
  int rbase = (w & 1) * 64;
  f32x4 acc[4][4];
  #pragma unroll
  for (int t = 0; t < 4; ++t)
    #pragma unroll
    for (int u = 0; u < 4; ++u) acc[t][u] = (f32x4)(0.f);

  #pragma unroll
  for (int i = 0; i < 8; ++i)
    stage8_64(ssrc, CCH, rbase + i * 8, 0, (w < 2) ? As[0] : Bs[0], lane);
  __syncthreads();

  for (int st = 0; st < 8; ++st) {
    int cur = st & 1;
    if (st < 7) {
      #pragma unroll
      for (int i = 0; i < 8; ++i)
        stage8_64(ssrc, CCH, rbase + i * 8, (st + 1) * 64,
                  (w < 2) ? As[cur ^ 1] : Bs[cur ^ 1], lane);
    }
    #pragma unroll
    for (int s = 0; s < 2; ++s) {
      int cl = s * 4 + (lane >> 4);
      bf16x8 a[4], bb[4];
      #pragma unroll
      for (int t = 0; t < 4; ++t) a[t] = fragld64(As[cur], qm * 64 + t * 16 + (lane & 15), cl);
      #pragma unroll
      for (int u = 0; u < 4; ++u) bb[u] = fragld64(Bs[cur], qn * 64 + u * 16 + (lane & 15), cl);
      #pragma unroll
      for (int t = 0; t < 4; ++t)
        #pragma unroll
        for (int u = 0; u < 4; ++u)
          acc[t][u] = __builtin_amdgcn_mfma_f32_16x16x32_bf16(a[t], bb[u], acc[t][u], 0, 0, 0);
    }
    __syncthreads();
  }
  #pragma unroll
  for (int t = 0; t < 4; ++t) {
    int row0 = bi * 128 + qm * 64 + t * 16 + (lane >> 4) * 4;
    #pragma unroll
    for (int u = 0; u < 4; ++u) {
      int col = bj * 128 + qn * 64 + u * 16 + (lane & 15);
      float cst = mconst[col];
      #pragma unroll
      for (int r4 = 0; r4 < 4; ++r4) {
        size_t o = (size_t)(row0 + r4) * CCH + col;
        out[o] = acc[t][u][r4] + cst + 0.2f * X[o];
      }
    }
  }
}

// ================================================================ launcher
extern "C" void kernel_launch(void* const* d_in, const int* in_sizes, int n_in,
                              void* d_out, int out_size, void* d_ws, size_t ws_size,
                              hipStream_t stream) {
  const float* Xc = (const float*)d_in[0];
  const float* Xs = (const float*)d_in[1];
  float* out = (float*)d_out;

  float* f = (float*)d_ws;
  float* sums   = f;                     // 1024 (written by gram_part fold)
  float* rowsum = f + 1024;              // 1024
  float* s16    = f + 2048;              // 16 buckets x 1024 = 16384 (zeroed)
  float* cov    = f + 2048 + 2 * MS;     // 2*MS
  float* snorm  = cov + 2 * MS;          // 8
  float* coef   = snorm + 8;             // 8
  float* mconst = coef + 8;              // 512
  float* Zf     = mconst + 512;          // 2*MS (fp32, reused for Zr)

  // Gram split-K partials live in d_out (dead until apply_mfma): 32 MiB exactly.
  float* Gp = (float*)d_out;

  u16* h   = (u16*)(Zf + 2 * MS);
  u16* fct = h;                          // 2*512*16384 u16 (dead after gram)
  u16* fcb = h + (size_t)2 * CCH * NPIX; // 16384*512 u16
  const size_t B2 = 2 * MS;
  u16* Anh  = fct + 0 * B2;
  u16* Anl  = fct + 1 * B2;
  u16* Y1   = fct + 2 * B2;
  u16* Ya   = fct + 3 * B2;
  u16* Z0   = fct + 4 * B2;
  u16* Z1   = fct + 5 * B2;
  u16* Tb   = fct + 6 * B2;
  u16* Zfsh = fct + 7 * B2;
  u16* Zfsl = fct + 8 * B2;
  u16* Ph   = fct + 9 * B2;
  u16* Pl   = fct + 10 * B2;
  u16* Qh   = fct + 11 * B2;
  u16* Ql   = fct + 12 * B2;
  u16* Zrsh = fct + 13 * B2;
  u16* Zrsl = fct + 14 * B2;
  u16* W2h  = fct + 15 * B2;
  u16* W2l  = W2h + MS;
  u16* Mb   = W2l + MS;

  // zero: sums + rowsum + 16-bucket colsum partials
  hipMemsetAsync(d_ws, 0, (2048 + 16384) * sizeof(float), stream);

  prep_k<<<dim3(256, 8, 2), 256, 0, stream>>>(Xc, Xs, s16, fct, fcb);
  gram_part<<<dim3(16, 16, 2), 256, 0, stream>>>(fct, Gp, s16, sums);
  gram_reduce<<<2048, 256, 0, stream>>>(Gp, sums, cov, rowsum);
  nsinit_k<<<2048, 256, 0, stream>>>(cov, rowsum, snorm, coef, Anh, Anl, Z0);

  // NS: boosted first step (in nsinit) + 2 full iterations + final Z-update
  // All matmuls 32x64 tiles: grid (8, 16, z)
  {
    MM16 y1{};
    y1.A[0] = Anh;      y1.B[0] = Z0;      y1.D[0] = Y1;
    y1.A[1] = Anh + MS; y1.B[1] = Z0 + MS; y1.D[1] = Y1 + MS;
    y1.scale = 1.f; y1.diag = 0.f; y1.outFp32 = 0;
    mm16_k<<<dim3(8, 16, 2), 256, 0, stream>>>(y1);
  }
  {
    MM16 t{};   // T0 = 3I - Z0 @ Y1
    t.A[0] = Z0;      t.B[0] = Y1;      t.D[0] = Tb;
    t.A[1] = Z0 + MS; t.B[1] = Y1 + MS; t.D[1] = Tb + MS;
    t.scale = -1.f; t.diag = 3.f; t.outFp32 = 0;
    mm16_k<<<dim3(8, 16, 2), 256, 0, stream>>>(t);
  }
  {
    MM16 yz{};  // Ya = Y1@T0/2 ; Z1 = T0@Z0/2
    yz.A[0] = Y1;      yz.B[0] = Tb;      yz.D[0] = Ya;
    yz.A[1] = Y1 + MS; yz.B[1] = Tb + MS; yz.D[1] = Ya + MS;
    yz.A[2] = Tb;      yz.B[2] = Z0;      yz.D[2] = Z1;
    yz.A[3] = Tb + MS; yz.B[3] = Z0 + MS; yz.D[3] = Z1 + MS;
    yz.scale = 0.5f; yz.diag = 0.f; yz.outFp32 = 0;
    mm16_k<<<dim3(8, 16, 4), 256, 0, stream>>>(yz);
  }
  {
    MM16 t{};   // T1 = 3I - Z1 @ Ya
    t.A[0] = Z1;      t.B[0] = Ya;      t.D[0] = Tb;
    t.A[1] = Z1 + MS; t.B[1] = Ya + MS; t.D[1] = Tb + MS;
    t.scale = -1.f; t.diag = 3.f; t.outFp32 = 0;
    mm16_k<<<dim3(8, 16, 2), 256, 0, stream>>>(t);
  }
  {
    MM16 yz{};  // Y1 = Ya@T1/2 ; Z0 = T1@Z1/2
    yz.A[0] = Ya;      yz.B[0] = Tb;      yz.D[0] = Y1;
    yz.A[1] = Ya + MS; yz.B[1] = Tb + MS; yz.D[1] = Y1 + MS;
    yz.A[2] = Tb;      yz.B[2] = Z1;      yz.D[2] = Z0;
    yz.A[3] = Tb + MS; yz.B[3] = Z1 + MS; yz.D[3] = Z0 + MS;
    yz.scale = 0.5f; yz.diag = 0.f; yz.outFp32 = 0;
    mm16_k<<<dim3(8, 16, 4), 256, 0, stream>>>(yz);
  }
  {
    MM16 t{};   // T2 = 3I - Z0 @ Y1
    t.A[0] = Z0;      t.B[0] = Y1;      t.D[0] = Tb;
    t.A[1] = Z0 + MS; t.B[1] = Y1 + MS; t.D[1] = Tb + MS;
    t.scale = -1.f; t.diag = 3.f; t.outFp32 = 0;
    mm16_k<<<dim3(8, 16, 2), 256, 0, stream>>>(t);
  }
  {
    MM16 zf{};  // Zf = T2 @ Z0 / 2  (fp32)
    zf.A[0] = Tb;      zf.B[0] = Z0;      zf.D[0] = Zf;
    zf.A[1] = Tb + MS; zf.B[1] = Z0 + MS; zf.D[1] = Zf + MS;
    zf.scale = 0.5f; zf.diag = 0.f; zf.outFp32 = 1;
    mm16_k<<<dim3(8, 16, 2), 256, 0, stream>>>(zf);
  }

  // symmetrize+split Zf
  symsplit_k<<<dim3(1024, 2), 256, 0, stream>>>(Zf, Zfsh, Zfsl);

  // P_b = Zfs_b @ An_b ; Q_b = Zfs_b @ Zfs_b
  MMS pq{};
  for (int b = 0; b < 2; ++b) {
    pq.Ah[b] = Zfsh + b * MS; pq.Al[b] = Zfsl + b * MS;
    pq.Bh[b] = Anh + b * MS;  pq.Bl[b] = Anl + b * MS;
    pq.Dh[b] = Ph + b * MS;   pq.Dl[b] = Pl + b * MS;
    pq.Ah[2 + b] = Zfsh + b * MS; pq.Al[2 + b] = Zfsl + b * MS;
    pq.Bh[2 + b] = Zfsh + b * MS; pq.Bl[2 + b] = Zfsl + b * MS;
    pq.Dh[2 + b] = Qh + b * MS;   pq.Dl[2 + b] = Ql + b * MS;
  }
  pq.scale = 1.f;
  mmsplit_k<<<dim3(8, 16, 4), 256, 0, stream>>>(pq);

  // Zr_b = 1.5 Zfs_b - 0.5 P_b @ Q_b  (fp32 out into Zf)
  MMS zr{};
  for (int b = 0; b < 2; ++b) {
    zr.Ah[b] = Ph + b * MS;   zr.Al[b] = Pl + b * MS;
    zr.Bh[b] = Qh + b * MS;   zr.Bl[b] = Ql + b * MS;
    zr.Eh[b] = Zfsh + b * MS; zr.El[b] = Zfsl + b * MS;
    zr.D32[b] = Zf + b * MS;
  }
  zr.scale = -0.5f; zr.beta = 1.5f;
  mmsplit_k<<<dim3(8, 16, 2), 256, 0, stream>>>(zr);

  // symmetrize+split Zr
  symsplit_k<<<dim3(1024, 2), 256, 0, stream>>>(Zf, Zrsh, Zrsl);

  // W2 = An_s @ Zrs_s (split out)
  MMS wv{};
  wv.Ah[0] = Anh + MS;  wv.Al[0] = Anl + MS;
  wv.Bh[0] = Zrsh + MS; wv.Bl[0] = Zrsl + MS;
  wv.Dh[0] = W2h; wv.Dl[0] = W2l;
  wv.scale = 1.f;
  mmsplit_k<<<dim3(8, 16, 1), 256, 0, stream>>>(wv);

  // M = coef * W2 @ Zrs_c (bf16 out)
  MMS mv{};
  mv.Ah[0] = W2h;  mv.Al[0] = W2l;
  mv.Bh[0] = Zrsh; mv.Bl[0] = Zrsl;
  mv.Db[0] = Mb;
  mv.scale = 1.f; mv.coefPtr = coef;
  mmsplit_k<<<dim3(8, 16, 1), 256, 0, stream>>>(mv);

  mconst_k<<<64, 256, 0, stream>>>(Mb, sums, mconst);
  apply_mfma<<<dim3(4, 128), 256, 0, stream>>>(fcb, Mb, mconst, Xc, out);
}